// Round 6
// baseline (158.633 us; speedup 1.0000x reference)
//
#include <hip/hip_runtime.h>
#include <math.h>

#define N_NODES 20000
#define N_EDGES 320000
#define CH      256
#define FEAT    118
#define CAP     48   // in-degree cap; dst ~ Poisson(16), P(any>48) ~ 2e-7 (fixed graph, verified)

typedef float    f32x4 __attribute__((ext_vector_type(4)));
typedef short    s16x8 __attribute__((ext_vector_type(8)));
typedef _Float16 f16x4 __attribute__((ext_vector_type(4)));
typedef _Float16 f16x8 __attribute__((ext_vector_type(8)));
typedef unsigned short u16;

union Frag { s16x8 v; u16 u[8]; };

__device__ __forceinline__ float gelu_exact(float x) {
    return 0.5f * x * (1.0f + erff(x * 0.70710678118654752f));
}
__device__ __forceinline__ u16 f2bf(float f) {
    unsigned u = __float_as_uint(f);
    u = (u + 0x7FFFu + ((u >> 16) & 1u)) >> 16;
    return (u16)u;
}
__device__ __forceinline__ float bf2f(u16 h) { return __uint_as_float(((unsigned)h) << 16); }

// fp16x8 -> split bf16 hi/lo (lossless: 11-bit mantissa fits in 8+8)
__device__ __forceinline__ void cvt_split(f16x8 a, s16x8& hi, s16x8& lo) {
    Frag H, L;
    #pragma unroll
    for (int e = 0; e < 8; e++) {
        float v = (float)a[e];
        u16 h = f2bf(v);
        H.u[e] = h; L.u[e] = f2bf(v - bf2f(h));
    }
    hi = H.v; lo = L.v;
}

// ---------------------------------------------------------------------------
// prep (fused): pack_x | fill_bins | pack W2 (B-frags) | compose Wc=We@W1, bc
//   A-frag [mt][ks][lane][8]: element j = A[mt*16+(lane&15)][ks*32+(lane>>4)*8+j]
//   B-frag [nt][ks][lane][8]: element j = B[ks*32+(lane>>4)*8+j][nt*16+(lane&15)]
// ---------------------------------------------------------------------------
__global__ __launch_bounds__(256) void prep(const float* __restrict__ x,
                                            const int* __restrict__ ei,
                                            const float* __restrict__ We,
                                            const float* __restrict__ be,
                                            const float* __restrict__ W1,
                                            const float* __restrict__ b1,
                                            const float* __restrict__ W2,
                                            u16* __restrict__ xh, u16* __restrict__ xl,
                                            int* __restrict__ cnt, int* __restrict__ bins,
                                            u16* __restrict__ w2h, u16* __restrict__ w2l,
                                            u16* __restrict__ wch, u16* __restrict__ wcl,
                                            float* __restrict__ bc) {
    const int b = blockIdx.x, tid = threadIdx.x;
    if (b < 1250) {                       // ---- pack_x: KS=4 (K=118 padded to 128)
        int fid = b * 256 + tid;
        int lane = fid & 63, ks = (fid >> 6) & 3, mt = fid >> 8;
        int row = mt * 16 + (lane & 15);
        int k0 = ks * 32 + (lane >> 4) * 8;
        Frag hi, lo;
        #pragma unroll
        for (int j = 0; j < 8; j++) {
            int k = k0 + j;
            float v = (k < FEAT) ? x[(size_t)row * FEAT + k] : 0.0f;
            u16 h = f2bf(v);
            hi.u[j] = h; lo.u[j] = f2bf(v - bf2f(h));
        }
        ((s16x8*)xh)[fid] = hi.v;
        ((s16x8*)xl)[fid] = lo.v;
    } else if (b < 2500) {                // ---- fill_bins
        int e = (b - 1250) * 256 + tid;
        int s = ei[e];
        int d = ei[N_EDGES + e];
        int p = atomicAdd(&cnt[d], 1);
        if (p < CAP) bins[(size_t)d * CAP + p] = s;
    } else if (b < 2532) {                // ---- pack W2 -> B-frags, KS=8
        int fid = (b - 2500) * 256 + tid;
        int lane = fid & 63, ks = (fid >> 6) & 7, nt = fid >> 9;
        int n = nt * 16 + (lane & 15);
        int k0 = ks * 32 + (lane >> 4) * 8;
        Frag hi, lo;
        #pragma unroll
        for (int j = 0; j < 8; j++) {
            float v = W2[(size_t)(k0 + j) * 256 + n];
            u16 h = f2bf(v);
            hi.u[j] = h; lo.u[j] = f2bf(v - bf2f(h));
        }
        ((s16x8*)w2h)[fid] = hi.v;
        ((s16x8*)w2l)[fid] = lo.v;
    } else {                              // ---- compose: Wc row f (f<128) or bc (f==128)
        int f = b - 2532;
        int n = tid;
        if (f < 128) {
            float acc = 0.0f;
            if (f < FEAT) {
                const float* wr = We + (size_t)f * 256;
                #pragma unroll 8
                for (int c = 0; c < 256; c++) acc += wr[c] * W1[(size_t)c * 256 + n];
            }
            int nt = n >> 4, lm = n & 15, ks = f >> 5, q = (f >> 3) & 3, j = f & 7;
            size_t idx = (((size_t)nt * 4 + ks) * 64 + q * 16 + lm) * 8 + j;
            u16 h = f2bf(acc);
            wch[idx] = h;
            wcl[idx] = f2bf(acc - bf2f(h));
        } else {
            float acc = b1[n];
            #pragma unroll 8
            for (int c = 0; c < 256; c++) acc += be[c] * W1[(size_t)c * 256 + n];
            bc[n] = acc;
        }
    }
}

// ---------------------------------------------------------------------------
// gemm_main: M = gelu(x @ Wc + bc), K=128 (KS=4), split-bf16 3-term MFMA.
// Wave tile 32x64. Output fp16 row-major via LDS bounce.
// ---------------------------------------------------------------------------
__global__ __launch_bounds__(256) void gemm_main(const u16* __restrict__ Ah_, const u16* __restrict__ Al_,
                                                 const u16* __restrict__ Bh_, const u16* __restrict__ Bl_,
                                                 const float* __restrict__ bias,
                                                 _Float16* __restrict__ Mout) {
    __shared__ _Float16 Ls[32][256];
    const int tid = threadIdx.x, wave = tid >> 6, lane = tid & 63;
    const int quad = lane >> 4, lm = lane & 15;
    const int mt0 = blockIdx.x * 2, nt0 = wave * 4;
    const s16x8* Ah = (const s16x8*)Ah_; const s16x8* Al = (const s16x8*)Al_;
    const s16x8* Bh = (const s16x8*)Bh_; const s16x8* Bl = (const s16x8*)Bl_;
    f32x4 acc[2][4];
    #pragma unroll
    for (int mi = 0; mi < 2; mi++)
        #pragma unroll
        for (int t = 0; t < 4; t++) acc[mi][t] = f32x4{0.f, 0.f, 0.f, 0.f};
    #pragma unroll
    for (int ks = 0; ks < 4; ks++) {
        s16x8 a0h = Ah[((size_t)(mt0 + 0) * 4 + ks) * 64 + lane];
        s16x8 a0l = Al[((size_t)(mt0 + 0) * 4 + ks) * 64 + lane];
        s16x8 a1h = Ah[((size_t)(mt0 + 1) * 4 + ks) * 64 + lane];
        s16x8 a1l = Al[((size_t)(mt0 + 1) * 4 + ks) * 64 + lane];
        #pragma unroll
        for (int t = 0; t < 4; t++) {
            s16x8 bh = Bh[((size_t)(nt0 + t) * 4 + ks) * 64 + lane];
            s16x8 bl = Bl[((size_t)(nt0 + t) * 4 + ks) * 64 + lane];
            acc[0][t] = __builtin_amdgcn_mfma_f32_16x16x32_bf16(a0h, bh, acc[0][t], 0, 0, 0);
            acc[0][t] = __builtin_amdgcn_mfma_f32_16x16x32_bf16(a0l, bh, acc[0][t], 0, 0, 0);
            acc[0][t] = __builtin_amdgcn_mfma_f32_16x16x32_bf16(a0h, bl, acc[0][t], 0, 0, 0);
            acc[1][t] = __builtin_amdgcn_mfma_f32_16x16x32_bf16(a1h, bh, acc[1][t], 0, 0, 0);
            acc[1][t] = __builtin_amdgcn_mfma_f32_16x16x32_bf16(a1l, bh, acc[1][t], 0, 0, 0);
            acc[1][t] = __builtin_amdgcn_mfma_f32_16x16x32_bf16(a1h, bl, acc[1][t], 0, 0, 0);
        }
    }
    #pragma unroll
    for (int t = 0; t < 4; t++) {
        float bn = bias[(nt0 + t) * 16 + lm];
        #pragma unroll
        for (int mi = 0; mi < 2; mi++)
            #pragma unroll
            for (int r = 0; r < 4; r++)
                Ls[mi * 16 + quad * 4 + r][(nt0 + t) * 16 + lm] =
                    (_Float16)gelu_exact(acc[mi][t][r] + bn);
    }
    __syncthreads();
    s16x8* dst = (s16x8*)Mout + (size_t)blockIdx.x * 1024;
    const s16x8* src = (const s16x8*)&Ls[0][0];
    #pragma unroll
    for (int it = 0; it < 4; it++)
        dst[it * 256 + tid] = src[it * 256 + tid];
}

// ---------------------------------------------------------------------------
// aggregate: one wave per node. 8-deep batched gathers (predicated tail via
// duplicate-index) -> 8 loads in flight per wave at full occupancy.
// Output row-major fp16 (coalesced 512B row stores).
// ---------------------------------------------------------------------------
__global__ __launch_bounds__(256) void aggregate(const _Float16* __restrict__ M,
                                                 const int* __restrict__ cnt,
                                                 const int* __restrict__ bins,
                                                 _Float16* __restrict__ agg) {
    int node = (blockIdx.x * 256 + threadIdx.x) >> 6;
    int lane = threadIdx.x & 63;
    int c = cnt[node];
    int cc = min(c, CAP);
    int myid = (lane < CAP) ? bins[(size_t)node * CAP + lane] : 0;
    float a0 = 0.f, a1 = 0.f, a2 = 0.f, a3 = 0.f;
    for (int j = 0; j < cc; j += 8) {
        f16x4 v[8];
        #pragma unroll
        for (int u = 0; u < 8; u++) {
            int s = __shfl(myid, min(j + u, cc - 1), 64);
            v[u] = *(const f16x4*)(M + (size_t)s * CH + lane * 4);
        }
        #pragma unroll
        for (int u = 0; u < 8; u++) {
            if (j + u < cc) {   // wave-uniform predicate
                a0 += (float)v[u].x; a1 += (float)v[u].y;
                a2 += (float)v[u].z; a3 += (float)v[u].w;
            }
        }
    }
    float inv = 1.0f / (float)max(c, 1);
    f16x4 o;
    o.x = (_Float16)(a0 * inv); o.y = (_Float16)(a1 * inv);
    o.z = (_Float16)(a2 * inv); o.w = (_Float16)(a3 * inv);
    *(f16x4*)(agg + (size_t)node * CH + lane * 4) = o;
}

// ---------------------------------------------------------------------------
// gemm_mean: out = mean_ch gelu(agg @ W2 + b2). Stages the 32x256 fp16 agg
// tile in LDS (coalesced), converts to split-bf16 fragments in registers.
// ---------------------------------------------------------------------------
#define LPITCH 264   // fp16 elements; 528B row stride keeps 16B align, spreads banks
__global__ __launch_bounds__(256) void gemm_mean(const _Float16* __restrict__ agg,
                                                 const u16* __restrict__ Bh_, const u16* __restrict__ Bl_,
                                                 const float* __restrict__ bias,
                                                 float* __restrict__ out) {
    __shared__ _Float16 Ls[32][LPITCH];
    __shared__ float part[4][32];
    const int tid = threadIdx.x, wave = tid >> 6, lane = tid & 63;
    const int quad = lane >> 4, lm = lane & 15;
    const int nt0 = wave * 4;
    // stage 32 rows x 256 ch fp16 (16KB) cooperatively, coalesced
    {
        const f16x8* src = (const f16x8*)(agg + (size_t)blockIdx.x * 32 * CH);
        #pragma unroll
        for (int it = 0; it < 4; it++) {
            int id = it * 256 + tid;          // chunk of 8 fp16
            int row = id >> 5, seg = id & 31;
            *(f16x8*)&Ls[row][seg * 8] = src[id];
        }
    }
    __syncthreads();
    const s16x8* Bh = (const s16x8*)Bh_; const s16x8* Bl = (const s16x8*)Bl_;
    f32x4 acc[2][4];
    #pragma unroll
    for (int mi = 0; mi < 2; mi++)
        #pragma unroll
        for (int t = 0; t < 4; t++) acc[mi][t] = f32x4{0.f, 0.f, 0.f, 0.f};
    #pragma unroll
    for (int ks = 0; ks < 8; ks++) {
        int c0 = ks * 32 + quad * 8;
        s16x8 a0h, a0l, a1h, a1l;
        cvt_split(*(const f16x8*)&Ls[lm][c0],      a0h, a0l);
        cvt_split(*(const f16x8*)&Ls[16 + lm][c0], a1h, a1l);
        #pragma unroll
        for (int t = 0; t < 4; t++) {
            s16x8 bh = Bh[((size_t)(nt0 + t) * 8 + ks) * 64 + lane];
            s16x8 bl = Bl[((size_t)(nt0 + t) * 8 + ks) * 64 + lane];
            acc[0][t] = __builtin_amdgcn_mfma_f32_16x16x32_bf16(a0h, bh, acc[0][t], 0, 0, 0);
            acc[0][t] = __builtin_amdgcn_mfma_f32_16x16x32_bf16(a0l, bh, acc[0][t], 0, 0, 0);
            acc[0][t] = __builtin_amdgcn_mfma_f32_16x16x32_bf16(a0h, bl, acc[0][t], 0, 0, 0);
            acc[1][t] = __builtin_amdgcn_mfma_f32_16x16x32_bf16(a1h, bh, acc[1][t], 0, 0, 0);
            acc[1][t] = __builtin_amdgcn_mfma_f32_16x16x32_bf16(a1l, bh, acc[1][t], 0, 0, 0);
            acc[1][t] = __builtin_amdgcn_mfma_f32_16x16x32_bf16(a1h, bl, acc[1][t], 0, 0, 0);
        }
    }
    float p[2][4] = {{0.f,0.f,0.f,0.f},{0.f,0.f,0.f,0.f}};
    #pragma unroll
    for (int t = 0; t < 4; t++) {
        float bn = bias[(nt0 + t) * 16 + lm];
        #pragma unroll
        for (int mi = 0; mi < 2; mi++)
            #pragma unroll
            for (int r = 0; r < 4; r++)
                p[mi][r] += gelu_exact(acc[mi][t][r] + bn);
    }
    #pragma unroll
    for (int off = 1; off < 16; off <<= 1)
        #pragma unroll
        for (int mi = 0; mi < 2; mi++)
            #pragma unroll
            for (int r = 0; r < 4; r++)
                p[mi][r] += __shfl_xor(p[mi][r], off, 64);
    if (lm == 0)
        #pragma unroll
        for (int mi = 0; mi < 2; mi++)
            #pragma unroll
            for (int r = 0; r < 4; r++)
                part[wave][mi * 16 + quad * 4 + r] = p[mi][r];
    __syncthreads();
    if (tid < 32) {
        float s = part[0][tid] + part[1][tid] + part[2][tid] + part[3][tid];
        out[blockIdx.x * 32 + tid] = s * (1.0f / 256.0f);
    }
}

extern "C" void kernel_launch(void* const* d_in, const int* in_sizes, int n_in,
                              void* d_out, int out_size, void* d_ws, size_t ws_size,
                              hipStream_t stream) {
    const float* x  = (const float*)d_in[0];
    const int*   ei = (const int*)d_in[1];
    const float* We = (const float*)d_in[2];
    const float* be = (const float*)d_in[3];
    const float* W1 = (const float*)d_in[4];
    const float* b1 = (const float*)d_in[5];
    const float* W2 = (const float*)d_in[6];
    const float* b2 = (const float*)d_in[7];
    float* out = (float*)d_out;

    // ws layout: xh/xl (10.24 MB) dead after gemm_main -> reused as agg (fp16).
    char* ws = (char*)d_ws;
    size_t off = 0;
    u16* xh = (u16*)(ws + off);                           // 5,120,000
    _Float16* agg = (_Float16*)(ws + off);                // 10,240,000 (overlaps xh/xl)
    off += 5120000;
    u16* xl = (u16*)(ws + off); off += 5120000;
    _Float16* M = (_Float16*)(ws + off); off += 10240000; // 20000*256 fp16
    u16* wch = (u16*)(ws + off); off += 65536;
    u16* wcl = (u16*)(ws + off); off += 65536;
    u16* w2h = (u16*)(ws + off); off += 131072;
    u16* w2l = (u16*)(ws + off); off += 131072;
    float* bc = (float*)(ws + off); off += 1024;
    int* cnt  = (int*)(ws + off); off += N_NODES * 4;
    int* bins = (int*)(ws + off); off += (size_t)N_NODES * CAP * 4;

    hipMemsetAsync(cnt, 0, N_NODES * sizeof(int), stream);
    prep<<<2661, 256, 0, stream>>>(x, ei, We, be, W1, b1, W2,
                                   xh, xl, cnt, bins, w2h, w2l, wch, wcl, bc);
    gemm_main<<<N_NODES / 32, 256, 0, stream>>>(xh, xl, wch, wcl, bc, M);
    aggregate<<<N_NODES / 4, 256, 0, stream>>>(M, cnt, bins, agg);
    gemm_mean<<<N_NODES / 32, 256, 0, stream>>>(agg, w2h, w2l, b2, out);
}

// Round 7
// 154.688 us; speedup vs baseline: 1.0255x; 1.0255x over previous
//
#include <hip/hip_runtime.h>
#include <math.h>

#define N_NODES 20000
#define N_EDGES 320000
#define CH      256
#define FEAT    118
#define CAP     48   // in-degree cap; dst ~ Poisson(16), P(any>48) ~ 2e-7

typedef float    f32x4 __attribute__((ext_vector_type(4)));
typedef short    s16x8 __attribute__((ext_vector_type(8)));
typedef _Float16 f16x4 __attribute__((ext_vector_type(4)));
typedef _Float16 f16x8 __attribute__((ext_vector_type(8)));
typedef unsigned short u16;

union Frag  { s16x8 v; u16 u[8]; };
union FragH { f16x8 v; _Float16 h[8]; };

__device__ __forceinline__ float gelu_exact(float x) {
    return 0.5f * x * (1.0f + erff(x * 0.70710678118654752f));
}
__device__ __forceinline__ u16 f2bf(float f) {
    unsigned u = __float_as_uint(f);
    u = (u + 0x7FFFu + ((u >> 16) & 1u)) >> 16;
    return (u16)u;
}
__device__ __forceinline__ float bf2f(u16 h) { return __uint_as_float(((unsigned)h) << 16); }

// ---------------------------------------------------------------------------
// prep (fused): pack_x (bf16 hi/lo A-frags) | fill_bins | pack W2 (fp16 wh +
// 4096-scaled wl B-frags) | compose Wc=We@W1 (bf16 hi/lo B-frags), bc
//   A-frag [mt][ks][lane][8]: elem j = A[mt*16+(lane&15)][ks*32+(lane>>4)*8+j]
//   B-frag [nt][ks][lane][8]: elem j = B[ks*32+(lane>>4)*8+j][nt*16+(lane&15)]
// ---------------------------------------------------------------------------
__global__ __launch_bounds__(256) void prep(const float* __restrict__ x,
                                            const int* __restrict__ ei,
                                            const float* __restrict__ We,
                                            const float* __restrict__ be,
                                            const float* __restrict__ W1,
                                            const float* __restrict__ b1,
                                            const float* __restrict__ W2,
                                            u16* __restrict__ xh, u16* __restrict__ xl,
                                            int* __restrict__ cnt, int* __restrict__ bins,
                                            _Float16* __restrict__ w2h, _Float16* __restrict__ w2l,
                                            u16* __restrict__ wch, u16* __restrict__ wcl,
                                            float* __restrict__ bc) {
    const int b = blockIdx.x, tid = threadIdx.x;
    if (b < 1250) {                       // ---- pack_x: KS=4 (K=118 padded to 128)
        int fid = b * 256 + tid;
        int lane = fid & 63, ks = (fid >> 6) & 3, mt = fid >> 8;
        int row = mt * 16 + (lane & 15);
        int k0 = ks * 32 + (lane >> 4) * 8;
        Frag hi, lo;
        #pragma unroll
        for (int j = 0; j < 8; j++) {
            int k = k0 + j;
            float v = (k < FEAT) ? x[(size_t)row * FEAT + k] : 0.0f;
            u16 h = f2bf(v);
            hi.u[j] = h; lo.u[j] = f2bf(v - bf2f(h));
        }
        ((s16x8*)xh)[fid] = hi.v;
        ((s16x8*)xl)[fid] = lo.v;
    } else if (b < 2500) {                // ---- fill_bins
        int e = (b - 1250) * 256 + tid;
        int s = ei[e];
        int d = ei[N_EDGES + e];
        int p = atomicAdd(&cnt[d], 1);
        if (p < CAP) bins[(size_t)d * CAP + p] = s;
    } else if (b < 2532) {                // ---- pack W2 -> fp16 wh + scaled wl B-frags, KS=8
        int fid = (b - 2500) * 256 + tid;
        int lane = fid & 63, ks = (fid >> 6) & 7, nt = fid >> 9;
        int n = nt * 16 + (lane & 15);
        int k0 = ks * 32 + (lane >> 4) * 8;
        FragH hi, lo;
        #pragma unroll
        for (int j = 0; j < 8; j++) {
            float v = W2[(size_t)(k0 + j) * 256 + n];
            _Float16 h = (_Float16)v;
            hi.h[j] = h;
            lo.h[j] = (_Float16)((v - (float)h) * 4096.0f);   // keep wl normal-range
        }
        ((f16x8*)w2h)[fid] = hi.v;
        ((f16x8*)w2l)[fid] = lo.v;
    } else {                              // ---- compose: Wc row f (f<128) or bc (f==128)
        int f = b - 2532;
        int n = tid;
        if (f < 128) {
            float acc = 0.0f;
            if (f < FEAT) {
                const float* wr = We + (size_t)f * 256;
                #pragma unroll 8
                for (int c = 0; c < 256; c++) acc += wr[c] * W1[(size_t)c * 256 + n];
            }
            int nt = n >> 4, lm = n & 15, ks = f >> 5, q = (f >> 3) & 3, j = f & 7;
            size_t idx = (((size_t)nt * 4 + ks) * 64 + q * 16 + lm) * 8 + j;
            u16 h = f2bf(acc);
            wch[idx] = h;
            wcl[idx] = f2bf(acc - bf2f(h));
        } else {
            float acc = b1[n];
            #pragma unroll 8
            for (int c = 0; c < 256; c++) acc += be[c] * W1[(size_t)c * 256 + n];
            bc[n] = acc;
        }
    }
}

// ---------------------------------------------------------------------------
// gemm_main: M = gelu(x @ Wc + bc), K=128 (KS=4), split-bf16 3-term MFMA.
// 16-row blocks (1250 -> ~19.5 waves/CU). Wave tile 16x64 (1 m x 4 n-tiles).
// Output fp16 row-major via LDS bounce.
// ---------------------------------------------------------------------------
__global__ __launch_bounds__(256) void gemm_main(const u16* __restrict__ Ah_, const u16* __restrict__ Al_,
                                                 const u16* __restrict__ Bh_, const u16* __restrict__ Bl_,
                                                 const float* __restrict__ bias,
                                                 _Float16* __restrict__ Mout) {
    __shared__ _Float16 Ls[16][256];
    const int tid = threadIdx.x, wave = tid >> 6, lane = tid & 63;
    const int quad = lane >> 4, lm = lane & 15;
    const int mt = blockIdx.x, nt0 = wave * 4;
    const s16x8* Ah = (const s16x8*)Ah_; const s16x8* Al = (const s16x8*)Al_;
    const s16x8* Bh = (const s16x8*)Bh_; const s16x8* Bl = (const s16x8*)Bl_;
    f32x4 acc[4] = {f32x4{0,0,0,0}, f32x4{0,0,0,0}, f32x4{0,0,0,0}, f32x4{0,0,0,0}};
    #pragma unroll
    for (int ks = 0; ks < 4; ks++) {
        s16x8 a_h = Ah[((size_t)mt * 4 + ks) * 64 + lane];
        s16x8 a_l = Al[((size_t)mt * 4 + ks) * 64 + lane];
        #pragma unroll
        for (int t = 0; t < 4; t++) {
            s16x8 bh = Bh[((size_t)(nt0 + t) * 4 + ks) * 64 + lane];
            s16x8 bl = Bl[((size_t)(nt0 + t) * 4 + ks) * 64 + lane];
            acc[t] = __builtin_amdgcn_mfma_f32_16x16x32_bf16(a_h, bh, acc[t], 0, 0, 0);
            acc[t] = __builtin_amdgcn_mfma_f32_16x16x32_bf16(a_l, bh, acc[t], 0, 0, 0);
            acc[t] = __builtin_amdgcn_mfma_f32_16x16x32_bf16(a_h, bl, acc[t], 0, 0, 0);
        }
    }
    #pragma unroll
    for (int t = 0; t < 4; t++) {
        float bn = bias[(nt0 + t) * 16 + lm];
        #pragma unroll
        for (int r = 0; r < 4; r++)
            Ls[quad * 4 + r][(nt0 + t) * 16 + lm] = (_Float16)gelu_exact(acc[t][r] + bn);
    }
    __syncthreads();
    s16x8* dst = (s16x8*)Mout + (size_t)mt * 512;   // 16 rows * 32 frags
    const s16x8* src = (const s16x8*)&Ls[0][0];
    dst[tid]       = src[tid];
    dst[256 + tid] = src[256 + tid];
}

// ---------------------------------------------------------------------------
// aggregate: one wave per node, 4-deep batched gathers (predicated tail).
// Output agg directly in packed-A fp16 fragment layout (KS=8) for gemm_mean.
// ---------------------------------------------------------------------------
__global__ __launch_bounds__(256) void aggregate(const _Float16* __restrict__ M,
                                                 const int* __restrict__ cnt,
                                                 const int* __restrict__ bins,
                                                 _Float16* __restrict__ aggf) {
    int node = (blockIdx.x * 256 + threadIdx.x) >> 6;
    int lane = threadIdx.x & 63;
    int c = cnt[node];
    int cc = min(c, CAP);
    int myid = (lane < CAP) ? bins[(size_t)node * CAP + lane] : 0;
    float a0 = 0.f, a1 = 0.f, a2 = 0.f, a3 = 0.f;
    for (int j = 0; j < cc; j += 4) {
        f16x4 v[4];
        #pragma unroll
        for (int u = 0; u < 4; u++) {
            int s = __shfl(myid, min(j + u, cc - 1), 64);
            v[u] = *(const f16x4*)(M + (size_t)s * CH + lane * 4);
        }
        #pragma unroll
        for (int u = 0; u < 4; u++) {
            if (j + u < cc) {   // wave-uniform predicate
                a0 += (float)v[u].x; a1 += (float)v[u].y;
                a2 += (float)v[u].z; a3 += (float)v[u].w;
            }
        }
    }
    float inv = 1.0f / (float)max(c, 1);
    f16x4 o;
    o.x = (_Float16)(a0 * inv); o.y = (_Float16)(a1 * inv);
    o.z = (_Float16)(a2 * inv); o.w = (_Float16)(a3 * inv);
    // ch = lane*4+q -> packed-A (KS=8): ks=lane>>3, quad=(lane&7)>>1, j0=(lane&1)*4
    int mt = node >> 4, lm = node & 15;
    int ks = lane >> 3, quad = (lane & 7) >> 1, j0 = (lane & 1) * 4;
    size_t base = (((size_t)mt * 8 + ks) * 64 + quad * 16 + lm) * 8 + j0;
    *(f16x4*)(aggf + base) = o;
}

// ---------------------------------------------------------------------------
// gemm_mean: out = mean_ch gelu(agg @ W2 + b2).
// A = exact fp16 packed frags (1 term); B = fp16 wh + 4096-scaled wl (2 acc
// sets, combined in epilogue). 32-row blocks, wave tile 2m x 4nt.
// ---------------------------------------------------------------------------
__global__ __launch_bounds__(256) void gemm_mean(const _Float16* __restrict__ Af_,
                                                 const _Float16* __restrict__ Bh_, const _Float16* __restrict__ Bl_,
                                                 const float* __restrict__ bias,
                                                 float* __restrict__ out) {
    __shared__ float part[4][32];
    const int tid = threadIdx.x, wave = tid >> 6, lane = tid & 63;
    const int quad = lane >> 4, lm = lane & 15;
    const int mt0 = blockIdx.x * 2, nt0 = wave * 4;
    const f16x8* Af = (const f16x8*)Af_;
    const f16x8* Bh = (const f16x8*)Bh_; const f16x8* Bl = (const f16x8*)Bl_;
    f32x4 acch[2][4], accl[2][4];
    #pragma unroll
    for (int mi = 0; mi < 2; mi++)
        #pragma unroll
        for (int t = 0; t < 4; t++) {
            acch[mi][t] = f32x4{0.f, 0.f, 0.f, 0.f};
            accl[mi][t] = f32x4{0.f, 0.f, 0.f, 0.f};
        }
    #pragma unroll
    for (int ks = 0; ks < 8; ks++) {
        f16x8 a0 = Af[((size_t)(mt0 + 0) * 8 + ks) * 64 + lane];
        f16x8 a1 = Af[((size_t)(mt0 + 1) * 8 + ks) * 64 + lane];
        #pragma unroll
        for (int t = 0; t < 4; t++) {
            f16x8 bh = Bh[((size_t)(nt0 + t) * 8 + ks) * 64 + lane];
            f16x8 bl = Bl[((size_t)(nt0 + t) * 8 + ks) * 64 + lane];
            acch[0][t] = __builtin_amdgcn_mfma_f32_16x16x32_f16(a0, bh, acch[0][t], 0, 0, 0);
            accl[0][t] = __builtin_amdgcn_mfma_f32_16x16x32_f16(a0, bl, accl[0][t], 0, 0, 0);
            acch[1][t] = __builtin_amdgcn_mfma_f32_16x16x32_f16(a1, bh, acch[1][t], 0, 0, 0);
            accl[1][t] = __builtin_amdgcn_mfma_f32_16x16x32_f16(a1, bl, accl[1][t], 0, 0, 0);
        }
    }
    float p[2][4] = {{0.f,0.f,0.f,0.f},{0.f,0.f,0.f,0.f}};
    #pragma unroll
    for (int t = 0; t < 4; t++) {
        float bn = bias[(nt0 + t) * 16 + lm];
        #pragma unroll
        for (int mi = 0; mi < 2; mi++)
            #pragma unroll
            for (int r = 0; r < 4; r++)
                p[mi][r] += gelu_exact(acch[mi][t][r] + accl[mi][t][r] * (1.0f / 4096.0f) + bn);
    }
    #pragma unroll
    for (int off = 1; off < 16; off <<= 1)
        #pragma unroll
        for (int mi = 0; mi < 2; mi++)
            #pragma unroll
            for (int r = 0; r < 4; r++)
                p[mi][r] += __shfl_xor(p[mi][r], off, 64);
    if (lm == 0)
        #pragma unroll
        for (int mi = 0; mi < 2; mi++)
            #pragma unroll
            for (int r = 0; r < 4; r++)
                part[wave][mi * 16 + quad * 4 + r] = p[mi][r];
    __syncthreads();
    if (tid < 32) {
        float s = part[0][tid] + part[1][tid] + part[2][tid] + part[3][tid];
        out[blockIdx.x * 32 + tid] = s * (1.0f / 256.0f);
    }
}

extern "C" void kernel_launch(void* const* d_in, const int* in_sizes, int n_in,
                              void* d_out, int out_size, void* d_ws, size_t ws_size,
                              hipStream_t stream) {
    const float* x  = (const float*)d_in[0];
    const int*   ei = (const int*)d_in[1];
    const float* We = (const float*)d_in[2];
    const float* be = (const float*)d_in[3];
    const float* W1 = (const float*)d_in[4];
    const float* b1 = (const float*)d_in[5];
    const float* W2 = (const float*)d_in[6];
    const float* b2 = (const float*)d_in[7];
    float* out = (float*)d_out;

    // ws layout: xh/xl (10.24 MB) dead after gemm_main -> reused as aggf (fp16).
    char* ws = (char*)d_ws;
    size_t off = 0;
    u16* xh = (u16*)(ws + off);                           // 5,120,000
    _Float16* aggf = (_Float16*)(ws + off);               // 10,240,000 (overlaps xh/xl)
    off += 5120000;
    u16* xl = (u16*)(ws + off); off += 5120000;
    _Float16* M = (_Float16*)(ws + off); off += 10240000; // 20000*256 fp16
    u16* wch = (u16*)(ws + off); off += 65536;            // Wc bf16 hi B-frags (K=128)
    u16* wcl = (u16*)(ws + off); off += 65536;
    _Float16* w2h = (_Float16*)(ws + off); off += 131072; // W2 fp16 wh B-frags (K=256)
    _Float16* w2l = (_Float16*)(ws + off); off += 131072; // W2 fp16 wl*4096
    float* bc = (float*)(ws + off); off += 1024;
    int* cnt  = (int*)(ws + off); off += N_NODES * 4;
    int* bins = (int*)(ws + off); off += (size_t)N_NODES * CAP * 4;

    hipMemsetAsync(cnt, 0, N_NODES * sizeof(int), stream);
    prep<<<2661, 256, 0, stream>>>(x, ei, We, be, W1, b1, W2,
                                   xh, xl, cnt, bins, w2h, w2l, wch, wcl, bc);
    gemm_main<<<N_NODES / 16, 256, 0, stream>>>(xh, xl, wch, wcl, bc, M);
    aggregate<<<N_NODES / 4, 256, 0, stream>>>(M, cnt, bins, aggf);
    gemm_mean<<<N_NODES / 32, 256, 0, stream>>>(aggf, w2h, w2l, b2, out);
}

// Round 8
// 151.734 us; speedup vs baseline: 1.0455x; 1.0195x over previous
//
#include <hip/hip_runtime.h>
#include <math.h>

#define N_NODES 20000
#define N_EDGES 320000
#define CH      256
#define FEAT    118
#define CAP     48   // in-degree cap; dst ~ Poisson(16), P(any>48) ~ 2e-7

typedef float    f32x4 __attribute__((ext_vector_type(4)));
typedef short    s16x8 __attribute__((ext_vector_type(8)));
typedef _Float16 f16x4 __attribute__((ext_vector_type(4)));
typedef _Float16 f16x8 __attribute__((ext_vector_type(8)));
typedef unsigned short u16;

union Frag  { s16x8 v; u16 u[8]; };
union FragH { f16x8 v; _Float16 h[8]; };

__device__ __forceinline__ float gelu_exact(float x) {
    return 0.5f * x * (1.0f + erff(x * 0.70710678118654752f));
}
__device__ __forceinline__ u16 f2bf(float f) {
    unsigned u = __float_as_uint(f);
    u = (u + 0x7FFFu + ((u >> 16) & 1u)) >> 16;
    return (u16)u;
}
__device__ __forceinline__ float bf2f(u16 h) { return __uint_as_float(((unsigned)h) << 16); }

// ---------------------------------------------------------------------------
// prep (fused): pack_x (LDS-bounce, bf16 hi/lo A-frags) | fill_bins |
// pack W2 (fp16 wh + 4096-scaled wl B-frags) | compose Wc=We@W1 (bf16 B-frags), bc
//   A-frag [mt][ks][lane][8]: elem j = A[mt*16+(lane&15)][ks*32+(lane>>4)*8+j]
//   B-frag [nt][ks][lane][8]: elem j = B[ks*32+(lane>>4)*8+j][nt*16+(lane&15)]
// ---------------------------------------------------------------------------
__global__ __launch_bounds__(256) void prep(const float* __restrict__ x,
                                            const int* __restrict__ ei,
                                            const float* __restrict__ We,
                                            const float* __restrict__ be,
                                            const float* __restrict__ W1,
                                            const float* __restrict__ b1,
                                            const float* __restrict__ W2,
                                            u16* __restrict__ xh, u16* __restrict__ xl,
                                            int* __restrict__ cnt, int* __restrict__ bins,
                                            _Float16* __restrict__ w2h, _Float16* __restrict__ w2l,
                                            u16* __restrict__ wch, u16* __restrict__ wcl,
                                            float* __restrict__ bc) {
    const int b = blockIdx.x, tid = threadIdx.x;
    if (b < 1250) {                       // ---- pack_x: block = one 16-row m-tile
        __shared__ float xs[16][132];     // pitch 132: 16B-aligned rows, bank stride 4
        {
            int r = tid >> 4, ci = tid & 15;
            const float* xrow = x + (size_t)(b * 16 + r) * FEAT;
            #pragma unroll
            for (int it = 0; it < 8; it++) {
                int col = ci + it * 16;
                xs[r][col] = (col < FEAT) ? xrow[col] : 0.0f;
            }
        }
        __syncthreads();
        int lane = tid & 63, ks = tid >> 6;
        int row = lane & 15, k0 = ks * 32 + (lane >> 4) * 8;
        Frag hi, lo;
        #pragma unroll
        for (int j = 0; j < 8; j++) {
            float v = xs[row][k0 + j];
            u16 h = f2bf(v);
            hi.u[j] = h; lo.u[j] = f2bf(v - bf2f(h));
        }
        size_t fid = (size_t)b * 256 + tid;   // == ((b*4+ks)*64+lane)
        ((s16x8*)xh)[fid] = hi.v;
        ((s16x8*)xl)[fid] = lo.v;
    } else if (b < 2500) {                // ---- fill_bins
        int e = (b - 1250) * 256 + tid;
        int s = ei[e];
        int d = ei[N_EDGES + e];
        int p = atomicAdd(&cnt[d], 1);
        if (p < CAP) bins[(size_t)d * CAP + p] = s;
    } else if (b < 2532) {                // ---- pack W2 -> fp16 wh + scaled wl B-frags, KS=8
        int fid = (b - 2500) * 256 + tid;
        int lane = fid & 63, ks = (fid >> 6) & 7, nt = fid >> 9;
        int n = nt * 16 + (lane & 15);
        int k0 = ks * 32 + (lane >> 4) * 8;
        FragH hi, lo;
        #pragma unroll
        for (int j = 0; j < 8; j++) {
            float v = W2[(size_t)(k0 + j) * 256 + n];
            _Float16 h = (_Float16)v;
            hi.h[j] = h;
            lo.h[j] = (_Float16)((v - (float)h) * 4096.0f);   // keep wl normal-range
        }
        ((f16x8*)w2h)[fid] = hi.v;
        ((f16x8*)w2l)[fid] = lo.v;
    } else {                              // ---- compose: Wc row f (f<128) or bc (f==128)
        int f = b - 2532;
        int n = tid;
        if (f < 128) {
            float acc = 0.0f;
            if (f < FEAT) {
                const float* wr = We + (size_t)f * 256;
                #pragma unroll 8
                for (int c = 0; c < 256; c++) acc += wr[c] * W1[(size_t)c * 256 + n];
            }
            int nt = n >> 4, lm = n & 15, ks = f >> 5, q = (f >> 3) & 3, j = f & 7;
            size_t idx = (((size_t)nt * 4 + ks) * 64 + q * 16 + lm) * 8 + j;
            u16 h = f2bf(acc);
            wch[idx] = h;
            wcl[idx] = f2bf(acc - bf2f(h));
        } else {
            float acc = b1[n];
            #pragma unroll 8
            for (int c = 0; c < 256; c++) acc += be[c] * W1[(size_t)c * 256 + n];
            bc[n] = acc;
        }
    }
}

// ---------------------------------------------------------------------------
// gemm_main: M = gelu(x @ Wc + bc), K=128 (KS=4), split-bf16 3-term MFMA.
// 16-row blocks (1250 -> ~19.5 waves/CU). Wave tile 16x64 (1 m x 4 n-tiles).
// Output fp16 row-major via LDS bounce.
// ---------------------------------------------------------------------------
__global__ __launch_bounds__(256) void gemm_main(const u16* __restrict__ Ah_, const u16* __restrict__ Al_,
                                                 const u16* __restrict__ Bh_, const u16* __restrict__ Bl_,
                                                 const float* __restrict__ bias,
                                                 _Float16* __restrict__ Mout) {
    __shared__ _Float16 Ls[16][256];
    const int tid = threadIdx.x, wave = tid >> 6, lane = tid & 63;
    const int quad = lane >> 4, lm = lane & 15;
    const int mt = blockIdx.x, nt0 = wave * 4;
    const s16x8* Ah = (const s16x8*)Ah_; const s16x8* Al = (const s16x8*)Al_;
    const s16x8* Bh = (const s16x8*)Bh_; const s16x8* Bl = (const s16x8*)Bl_;
    f32x4 acc[4] = {f32x4{0,0,0,0}, f32x4{0,0,0,0}, f32x4{0,0,0,0}, f32x4{0,0,0,0}};
    #pragma unroll
    for (int ks = 0; ks < 4; ks++) {
        s16x8 a_h = Ah[((size_t)mt * 4 + ks) * 64 + lane];
        s16x8 a_l = Al[((size_t)mt * 4 + ks) * 64 + lane];
        #pragma unroll
        for (int t = 0; t < 4; t++) {
            s16x8 bh = Bh[((size_t)(nt0 + t) * 4 + ks) * 64 + lane];
            s16x8 bl = Bl[((size_t)(nt0 + t) * 4 + ks) * 64 + lane];
            acc[t] = __builtin_amdgcn_mfma_f32_16x16x32_bf16(a_h, bh, acc[t], 0, 0, 0);
            acc[t] = __builtin_amdgcn_mfma_f32_16x16x32_bf16(a_l, bh, acc[t], 0, 0, 0);
            acc[t] = __builtin_amdgcn_mfma_f32_16x16x32_bf16(a_h, bl, acc[t], 0, 0, 0);
        }
    }
    #pragma unroll
    for (int t = 0; t < 4; t++) {
        float bn = bias[(nt0 + t) * 16 + lm];
        #pragma unroll
        for (int r = 0; r < 4; r++)
            Ls[quad * 4 + r][(nt0 + t) * 16 + lm] = (_Float16)gelu_exact(acc[t][r] + bn);
    }
    __syncthreads();
    s16x8* dst = (s16x8*)Mout + (size_t)mt * 512;   // 16 rows * 32 frags
    const s16x8* src = (const s16x8*)&Ls[0][0];
    dst[tid]       = src[tid];
    dst[256 + tid] = src[256 + tid];
}

// ---------------------------------------------------------------------------
// aggregate: one wave per node, 8-deep batched gathers. Tail duplicates via
// min-clamp re-load the SAME row -> L1 hits (cheap); adds exactly predicated.
// Output agg directly in packed-A fp16 fragment layout (KS=8) for gemm_mean.
// ---------------------------------------------------------------------------
__global__ __launch_bounds__(256) void aggregate(const _Float16* __restrict__ M,
                                                 const int* __restrict__ cnt,
                                                 const int* __restrict__ bins,
                                                 _Float16* __restrict__ aggf) {
    int node = (blockIdx.x * 256 + threadIdx.x) >> 6;
    int lane = threadIdx.x & 63;
    int c = cnt[node];
    int cc = min(c, CAP);
    int myid = (lane < CAP) ? bins[(size_t)node * CAP + lane] : 0;
    float a0 = 0.f, a1 = 0.f, a2 = 0.f, a3 = 0.f;
    for (int j = 0; j < cc; j += 8) {
        f16x4 v[8];
        #pragma unroll
        for (int u = 0; u < 8; u++) {
            int s = __shfl(myid, min(j + u, cc - 1), 64);
            v[u] = *(const f16x4*)(M + (size_t)s * CH + lane * 4);
        }
        #pragma unroll
        for (int u = 0; u < 8; u++) {
            if (j + u < cc) {   // wave-uniform predicate
                a0 += (float)v[u].x; a1 += (float)v[u].y;
                a2 += (float)v[u].z; a3 += (float)v[u].w;
            }
        }
    }
    float inv = 1.0f / (float)max(c, 1);
    f16x4 o;
    o.x = (_Float16)(a0 * inv); o.y = (_Float16)(a1 * inv);
    o.z = (_Float16)(a2 * inv); o.w = (_Float16)(a3 * inv);
    // ch = lane*4+q -> packed-A (KS=8): ks=lane>>3, quad=(lane&7)>>1, j0=(lane&1)*4
    int mt = node >> 4, lm = node & 15;
    int ks = lane >> 3, quad = (lane & 7) >> 1, j0 = (lane & 1) * 4;
    size_t base = (((size_t)mt * 8 + ks) * 64 + quad * 16 + lm) * 8 + j0;
    *(f16x4*)(aggf + base) = o;
}

// ---------------------------------------------------------------------------
// gemm_mean: out = mean_ch gelu(agg @ W2 + b2).
// A = exact fp16 packed frags (1 term); B = fp16 wh + 4096-scaled wl (2 acc
// sets, combined in epilogue). 32-row blocks, wave tile 2m x 4nt.
// ---------------------------------------------------------------------------
__global__ __launch_bounds__(256) void gemm_mean(const _Float16* __restrict__ Af_,
                                                 const _Float16* __restrict__ Bh_, const _Float16* __restrict__ Bl_,
                                                 const float* __restrict__ bias,
                                                 float* __restrict__ out) {
    __shared__ float part[4][32];
    const int tid = threadIdx.x, wave = tid >> 6, lane = tid & 63;
    const int quad = lane >> 4, lm = lane & 15;
    const int mt0 = blockIdx.x * 2, nt0 = wave * 4;
    const f16x8* Af = (const f16x8*)Af_;
    const f16x8* Bh = (const f16x8*)Bh_; const f16x8* Bl = (const f16x8*)Bl_;
    f32x4 acch[2][4], accl[2][4];
    #pragma unroll
    for (int mi = 0; mi < 2; mi++)
        #pragma unroll
        for (int t = 0; t < 4; t++) {
            acch[mi][t] = f32x4{0.f, 0.f, 0.f, 0.f};
            accl[mi][t] = f32x4{0.f, 0.f, 0.f, 0.f};
        }
    #pragma unroll
    for (int ks = 0; ks < 8; ks++) {
        f16x8 a0 = Af[((size_t)(mt0 + 0) * 8 + ks) * 64 + lane];
        f16x8 a1 = Af[((size_t)(mt0 + 1) * 8 + ks) * 64 + lane];
        #pragma unroll
        for (int t = 0; t < 4; t++) {
            f16x8 bh = Bh[((size_t)(nt0 + t) * 8 + ks) * 64 + lane];
            f16x8 bl = Bl[((size_t)(nt0 + t) * 8 + ks) * 64 + lane];
            acch[0][t] = __builtin_amdgcn_mfma_f32_16x16x32_f16(a0, bh, acch[0][t], 0, 0, 0);
            accl[0][t] = __builtin_amdgcn_mfma_f32_16x16x32_f16(a0, bl, accl[0][t], 0, 0, 0);
            acch[1][t] = __builtin_amdgcn_mfma_f32_16x16x32_f16(a1, bh, acch[1][t], 0, 0, 0);
            accl[1][t] = __builtin_amdgcn_mfma_f32_16x16x32_f16(a1, bl, accl[1][t], 0, 0, 0);
        }
    }
    float p[2][4] = {{0.f,0.f,0.f,0.f},{0.f,0.f,0.f,0.f}};
    #pragma unroll
    for (int t = 0; t < 4; t++) {
        float bn = bias[(nt0 + t) * 16 + lm];
        #pragma unroll
        for (int mi = 0; mi < 2; mi++)
            #pragma unroll
            for (int r = 0; r < 4; r++)
                p[mi][r] += gelu_exact(acch[mi][t][r] + accl[mi][t][r] * (1.0f / 4096.0f) + bn);
    }
    #pragma unroll
    for (int off = 1; off < 16; off <<= 1)
        #pragma unroll
        for (int mi = 0; mi < 2; mi++)
            #pragma unroll
            for (int r = 0; r < 4; r++)
                p[mi][r] += __shfl_xor(p[mi][r], off, 64);
    if (lm == 0)
        #pragma unroll
        for (int mi = 0; mi < 2; mi++)
            #pragma unroll
            for (int r = 0; r < 4; r++)
                part[wave][mi * 16 + quad * 4 + r] = p[mi][r];
    __syncthreads();
    if (tid < 32) {
        float s = part[0][tid] + part[1][tid] + part[2][tid] + part[3][tid];
        out[blockIdx.x * 32 + tid] = s * (1.0f / 256.0f);
    }
}

extern "C" void kernel_launch(void* const* d_in, const int* in_sizes, int n_in,
                              void* d_out, int out_size, void* d_ws, size_t ws_size,
                              hipStream_t stream) {
    const float* x  = (const float*)d_in[0];
    const int*   ei = (const int*)d_in[1];
    const float* We = (const float*)d_in[2];
    const float* be = (const float*)d_in[3];
    const float* W1 = (const float*)d_in[4];
    const float* b1 = (const float*)d_in[5];
    const float* W2 = (const float*)d_in[6];
    const float* b2 = (const float*)d_in[7];
    float* out = (float*)d_out;

    // ws layout: xh/xl (10.24 MB) dead after gemm_main -> reused as aggf (fp16).
    char* ws = (char*)d_ws;
    size_t off = 0;
    u16* xh = (u16*)(ws + off);                           // 5,120,000
    _Float16* aggf = (_Float16*)(ws + off);               // 10,240,000 (overlaps xh/xl)
    off += 5120000;
    u16* xl = (u16*)(ws + off); off += 5120000;
    _Float16* M = (_Float16*)(ws + off); off += 10240000; // 20000*256 fp16
    u16* wch = (u16*)(ws + off); off += 65536;            // Wc bf16 hi B-frags (K=128)
    u16* wcl = (u16*)(ws + off); off += 65536;
    _Float16* w2h = (_Float16*)(ws + off); off += 131072; // W2 fp16 wh B-frags (K=256)
    _Float16* w2l = (_Float16*)(ws + off); off += 131072; // W2 fp16 wl*4096
    float* bc = (float*)(ws + off); off += 1024;
    int* cnt  = (int*)(ws + off); off += N_NODES * 4;
    int* bins = (int*)(ws + off); off += (size_t)N_NODES * CAP * 4;

    hipMemsetAsync(cnt, 0, N_NODES * sizeof(int), stream);
    prep<<<2661, 256, 0, stream>>>(x, ei, We, be, W1, b1, W2,
                                   xh, xl, cnt, bins, w2h, w2l, wch, wcl, bc);
    gemm_main<<<N_NODES / 16, 256, 0, stream>>>(xh, xl, wch, wcl, bc, M);
    aggregate<<<N_NODES / 4, 256, 0, stream>>>(M, cnt, bins, aggf);
    gemm_mean<<<N_NODES / 32, 256, 0, stream>>>(aggf, w2h, w2l, b2, out);
}